// Round 5
// baseline (468.505 us; speedup 1.0000x reference)
//
#include <hip/hip_runtime.h>
#include <hip/hip_bf16.h>

// ---------------------------------------------------------------------------
// MHA forward: fp32 I/O, bf16 MFMA compute. B=4,S=2048,D=1024,H=16,DK=64.
//   0. cvt fp32->bf16 (X's + weights)
//   1. fused QKV projections (grid.z=3): Qh,Kh [B,H,S,64]; Vt [B,H,64,S]
//   2. flash attention, 64 q/wave, sum-only softmax
//   3. out = ctx@Wo^T+bo (fp32)
// GEMM operand roles: Q/K/O use A=W (packed stores along feature dim),
// V uses A=X (packed stores along s for the transposed layout).
// ---------------------------------------------------------------------------

typedef float  f32x4  __attribute__((ext_vector_type(4)));
typedef __bf16 bf16x8 __attribute__((ext_vector_type(8)));
typedef short  s16x8  __attribute__((ext_vector_type(8)));
typedef short  s16x4  __attribute__((ext_vector_type(4)));

#define MFMA16(a,b,c) __builtin_amdgcn_mfma_f32_16x16x32_bf16((a),(b),(c),0,0,0)

__device__ __forceinline__ unsigned short f2bf(float f) {
    union { float f; unsigned u; } v; v.f = f;
    unsigned r = v.u + 0x7fffu + ((v.u >> 16) & 1u);   // RNE
    return (unsigned short)(r >> 16);
}

__device__ __forceinline__ s16x8 cvt8(const float* __restrict__ p) {
    f32x4 x = *(const f32x4*)p;
    f32x4 y = *(const f32x4*)(p + 4);
    s16x8 r;
    r[0] = (short)f2bf(x[0]); r[1] = (short)f2bf(x[1]);
    r[2] = (short)f2bf(x[2]); r[3] = (short)f2bf(x[3]);
    r[4] = (short)f2bf(y[0]); r[5] = (short)f2bf(y[1]);
    r[6] = (short)f2bf(y[2]); r[7] = (short)f2bf(y[3]);
    return r;
}

__device__ __forceinline__ void gl_lds16(const void* g, void* l) {
    __builtin_amdgcn_global_load_lds(
        (const __attribute__((address_space(1))) unsigned int*)g,
        (__attribute__((address_space(3))) unsigned int*)l, 16, 0, 0);
}

// ---------------------------------------------------------------------------
__global__ __launch_bounds__(256) void cvt_kernel(
    const float* __restrict__ src, unsigned short* __restrict__ dst, int n8)
{
    int i = blockIdx.x * 256 + threadIdx.x;
    if (i < n8) *(s16x8*)(dst + (size_t)i * 8) = cvt8(src + (size_t)i * 8);
}

// ---------------------------------------------------------------------------
// Unified bf16 GEMM, 128x128 tile, BK=32, global_load_lds staging.
// D[arow, bcol] = sum_k A[arow,k]*B[bcol,k] + bias
// mode 0: A=W(f), B=X(m); store bf16 [B,H,S,64] packed along d (s16x4)
// mode 1: A=W(f), B=ctx(m); store fp32 [m,1024] packed along f (f32x4)
// mode 2: A=X(m), B=W(f); store bf16 [B,H,64,S] packed along s (s16x4)
// grid (64, 8, z): modes 0/1: A-tile=blockIdx.y, B-tile=blockIdx.x; mode 2 swapped.
// ---------------------------------------------------------------------------
__global__ __launch_bounds__(256) void gemm_fused(
    const unsigned short* __restrict__ A0, const unsigned short* __restrict__ B0,
    const float* __restrict__ c0, void* __restrict__ d0, int m0_,
    const unsigned short* __restrict__ A1, const unsigned short* __restrict__ B1,
    const float* __restrict__ c1, void* __restrict__ d1, int m1_,
    const unsigned short* __restrict__ A2, const unsigned short* __restrict__ B2,
    const float* __restrict__ c2, void* __restrict__ d2, int m2_,
    int zforce)
{
    const int z = (zforce >= 0) ? zforce : (int)blockIdx.z;
    const unsigned short* A = (z == 0) ? A0 : (z == 1) ? A1 : A2;
    const unsigned short* B = (z == 0) ? B0 : (z == 1) ? B1 : B2;
    const float* bias       = (z == 0) ? c0 : (z == 1) ? c1 : c2;
    void* dst               = (z == 0) ? d0 : (z == 1) ? d1 : d2;
    const int mode          = (z == 0) ? m0_ : (z == 1) ? m1_ : m2_;

    constexpr int K = 1024;
    __shared__ unsigned short Ash[128 * 32];
    __shared__ unsigned short Bsh[128 * 32];

    const int t    = threadIdx.x;
    const int w    = t >> 6;
    const int wm   = w >> 1, wn = w & 1;
    const int lane = t & 63;
    const int lr   = lane & 15, quad = lane >> 4;

    const int ta = (mode == 2) ? (int)blockIdx.x : (int)blockIdx.y;
    const int tb = (mode == 2) ? (int)blockIdx.y : (int)blockIdx.x;
    const int a0 = ta * 128;
    const int b0 = tb * 128;

    const int srow = t >> 2;          // 0..63
    const int skp  = (t & 3) * 8;

    const unsigned short* Ap0 = A + (size_t)(a0 + srow) * K + skp;
    const unsigned short* Ap1 = Ap0 + (size_t)64 * K;
    const unsigned short* Bp0 = B + (size_t)(b0 + srow) * K + skp;
    const unsigned short* Bp1 = Bp0 + (size_t)64 * K;
    unsigned short* lA0 = &Ash[w * 512];
    unsigned short* lA1 = &Ash[2048 + w * 512];
    unsigned short* lB0 = &Bsh[w * 512];
    unsigned short* lB1 = &Bsh[2048 + w * 512];

    f32x4 acc[4][4] = {};

    for (int k0 = 0; k0 < K; k0 += 32) {
        __syncthreads();
        gl_lds16(Ap0 + k0, lA0);
        gl_lds16(Ap1 + k0, lA1);
        gl_lds16(Bp0 + k0, lB0);
        gl_lds16(Bp1 + k0, lB1);
        __syncthreads();

        bf16x8 af[4], bw[4];
#pragma unroll
        for (int i = 0; i < 4; i++)
            af[i] = *(const bf16x8*)&Ash[(wm * 64 + i * 16 + lr) * 32 + quad * 8];
#pragma unroll
        for (int j = 0; j < 4; j++)
            bw[j] = *(const bf16x8*)&Bsh[(wn * 64 + j * 16 + lr) * 32 + quad * 8];

#pragma unroll
        for (int i = 0; i < 4; i++)
#pragma unroll
            for (int j = 0; j < 4; j++)
                acc[i][j] = MFMA16(af[i], bw[j], acc[i][j]);
    }

    // D rows (quad*4+r) = A-side, cols (lr) = B-side
#pragma unroll
    for (int i = 0; i < 4; i++) {
#pragma unroll
        for (int j = 0; j < 4; j++) {
            const int fa = a0 + wm * 64 + i * 16 + quad * 4;   // 4 regs: fa..fa+3
            const int cb = b0 + wn * 64 + j * 16 + lr;
            if (mode == 0) {
                f32x4 bb = *(const f32x4*)(bias + fa);
                const int h = fa >> 6, d = fa & 63;
                const int bb_ = cb >> 11, s = cb & 2047;
                s16x4 pk;
#pragma unroll
                for (int r = 0; r < 4; r++) pk[r] = (short)f2bf(acc[i][j][r] + bb[r]);
                *(s16x4*)((unsigned short*)dst +
                          (((size_t)(bb_ * 16 + h) * 2048 + s) << 6) + d) = pk;
            } else if (mode == 1) {
                f32x4 bb = *(const f32x4*)(bias + fa);
                f32x4 v  = acc[i][j] + bb;
                *(f32x4*)((float*)dst + (size_t)cb * 1024 + fa) = v;
            } else {
                const float bb = bias[cb];
                const int h = cb >> 6, d = cb & 63;
                const int bb_ = fa >> 11, s = fa & 2047;
                s16x4 pk;
#pragma unroll
                for (int r = 0; r < 4; r++) pk[r] = (short)f2bf(acc[i][j][r] + bb);
                *(s16x4*)((unsigned short*)dst +
                          ((size_t)(bb_ * 16 + h) * 64 + d) * 2048 + s) = pk;
            }
        }
    }
}

// ---------------------------------------------------------------------------
// Flash attention, sum-only softmax. Qh,Kh [B,H,S,64]; Vt [B,H,64,S] bf16.
// ctx out [B,S,1024] bf16. Grid (8 qblk, 64 bh). Block 256 = 4 waves.
// Each wave: 64 q rows (4 sub-tiles of 16) x full K loop, BK=64.
// K/V B-fragments loaded once per iter, reused by 4 sub-tiles (4x amortize).
// ---------------------------------------------------------------------------
__global__ __launch_bounds__(256) void attn_kernel(
    const unsigned short* __restrict__ Qh,
    const unsigned short* __restrict__ Kh,
    const unsigned short* __restrict__ Vt,
    unsigned short* __restrict__ ctx)
{
    constexpr int KS = 72;
    __shared__ unsigned short Ksh[64 * KS];      // [k][d]
    __shared__ unsigned short Vts[64 * KS];      // [d][k]
    __shared__ unsigned short Psh[4][64 * KS];   // wave-private [q][k]

    const int t    = threadIdx.x;
    const int w    = t >> 6;
    const int lane = t & 63;
    const int lr   = lane & 15, quad = lane >> 4;

    const int bh = blockIdx.y, qblk = blockIdx.x;
    const size_t base = (size_t)bh * 2048 * 64;
    const unsigned short* Qp = Qh + base;
    const unsigned short* Kg = Kh + base + (size_t)lane * 64 + w * 16;
    const unsigned short* Vg = Vt + base + (size_t)lane * 2048 + w * 16;

    const int q0 = qblk * 256 + w * 64;

    bf16x8 aq0[4], aq1[4];
#pragma unroll
    for (int s4 = 0; s4 < 4; s4++) {
        const unsigned short* qp = Qp + (size_t)(q0 + s4 * 16 + lr) * 64 + quad * 8;
        aq0[s4] = *(const bf16x8*)qp;
        aq1[s4] = *(const bf16x8*)(qp + 32);
    }

    f32x4 Of[4][4] = {};          // [sub][dt]
    float lsum[4][4] = {};        // [sub][r]

    for (int kb = 0; kb < 2048; kb += 64) {
        s16x8 kv0 = *(const s16x8*)(Kg + (size_t)kb * 64);
        s16x8 kv1 = *(const s16x8*)(Kg + (size_t)kb * 64 + 8);
        s16x8 vv0 = *(const s16x8*)(Vg + kb);
        s16x8 vv1 = *(const s16x8*)(Vg + kb + 8);

        __syncthreads();   // prior iteration's LDS reads complete
        *(s16x8*)&Ksh[lane * KS + w * 16]     = kv0;
        *(s16x8*)&Ksh[lane * KS + w * 16 + 8] = kv1;
        *(s16x8*)&Vts[lane * KS + w * 16]     = vv0;
        *(s16x8*)&Vts[lane * KS + w * 16 + 8] = vv1;
        __syncthreads();

        // ---- QK^T: B-frags once, reused by 4 q-subtiles. kcol = 16nt+lr.
        bf16x8 bk0[4], bk1[4];
#pragma unroll
        for (int nt = 0; nt < 4; nt++) {
            const unsigned short* kr = &Ksh[(16 * nt + lr) * KS + quad * 8];
            bk0[nt] = *(const bf16x8*)kr;
            bk1[nt] = *(const bf16x8*)(kr + 32);
        }
#pragma unroll
        for (int sub = 0; sub < 4; sub++) {
            f32x4 sc[4];
#pragma unroll
            for (int nt = 0; nt < 4; nt++) {
                f32x4 c = {};
                c = MFMA16(aq0[sub], bk0[nt], c);
                c = MFMA16(aq1[sub], bk1[nt], c);
                sc[nt] = c;
            }
#pragma unroll
            for (int r = 0; r < 4; r++) {
                float p0 = __expf(sc[0][r] * 0.125f);
                float p1 = __expf(sc[1][r] * 0.125f);
                float p2 = __expf(sc[2][r] * 0.125f);
                float p3 = __expf(sc[3][r] * 0.125f);
                lsum[sub][r] += (p0 + p1) + (p2 + p3);
                unsigned short* pr = &Psh[w][(sub * 16 + quad * 4 + r) * KS + lr];
                pr[0]  = f2bf(p0);
                pr[16] = f2bf(p1);
                pr[32] = f2bf(p2);
                pr[48] = f2bf(p3);
            }
        }
        __asm__ __volatile__("s_waitcnt lgkmcnt(0)" ::: "memory");

        // ---- PV: V B-frags once, reused by 4 q-subtiles
        bf16x8 bv0[4], bv1[4];
#pragma unroll
        for (int dt = 0; dt < 4; dt++) {
            const unsigned short* vr = &Vts[(dt * 16 + lr) * KS + quad * 8];
            bv0[dt] = *(const bf16x8*)vr;
            bv1[dt] = *(const bf16x8*)(vr + 32);
        }
#pragma unroll
        for (int sub = 0; sub < 4; sub++) {
            const unsigned short* pp = &Psh[w][(sub * 16 + lr) * KS + quad * 8];
            bf16x8 pf0 = *(const bf16x8*)pp;
            bf16x8 pf1 = *(const bf16x8*)(pp + 32);
#pragma unroll
            for (int dt = 0; dt < 4; dt++) {
                Of[sub][dt] = MFMA16(pf0, bv0[dt], Of[sub][dt]);
                Of[sub][dt] = MFMA16(pf1, bv1[dt], Of[sub][dt]);
            }
        }
    }

    // epilogue
    const int b = bh >> 4, h = bh & 15;
#pragma unroll
    for (int sub = 0; sub < 4; sub++) {
#pragma unroll
        for (int r = 0; r < 4; r++) {
            float l = lsum[sub][r];
            l += __shfl_xor(l, 1);
            l += __shfl_xor(l, 2);
            l += __shfl_xor(l, 4);
            l += __shfl_xor(l, 8);
            const float inv = 1.0f / l;
            const int q = q0 + sub * 16 + quad * 4 + r;
            unsigned short* cp = ctx + ((size_t)b * 2048 + q) * 1024 + h * 64;
#pragma unroll
            for (int dt = 0; dt < 4; dt++)
                cp[dt * 16 + lr] = f2bf(Of[sub][dt][r] * inv);
        }
    }
}

// ---------------------------------------------------------------------------
extern "C" void kernel_launch(void* const* d_in, const int* in_sizes, int n_in,
                              void* d_out, int out_size, void* d_ws, size_t ws_size,
                              hipStream_t stream) {
    const float* Q  = (const float*)d_in[0];
    const float* K  = (const float*)d_in[1];
    const float* V  = (const float*)d_in[2];
    const float* Wq = (const float*)d_in[3];
    const float* bq = (const float*)d_in[4];
    const float* Wk = (const float*)d_in[5];
    const float* bk = (const float*)d_in[6];
    const float* Wv = (const float*)d_in[7];
    const float* bv = (const float*)d_in[8];
    const float* Wo = (const float*)d_in[9];
    const float* bo = (const float*)d_in[10];

    const size_t EB = (size_t)8192 * 1024;   // 8 Mi elems (16 MB bf16)
    const size_t EW = (size_t)1024 * 1024;
    const int n8b = (int)(EB / 8), n8w = (int)(EW / 8);
    dim3 tb(256);

    const bool fused = ws_size >= (6 * EB + 4 * EW) * 2;

    if (fused) {
        unsigned short* Xq  = (unsigned short*)d_ws;
        unsigned short* Xk  = Xq + EB;
        unsigned short* Xv  = Xk + EB;
        unsigned short* Wqb = Xv + EB;
        unsigned short* Wkb = Wqb + EW;
        unsigned short* Wvb = Wkb + EW;
        unsigned short* Wob = Wvb + EW;
        unsigned short* Qh  = Wob + EW;
        unsigned short* Kh  = Qh + EB;
        unsigned short* Vtw = Kh + EB;
        unsigned short* Ctx = Xq;            // Xq dead after QKV GEMM

        cvt_kernel<<<n8w / 256, tb, 0, stream>>>(Wq, Wqb, n8w);
        cvt_kernel<<<n8w / 256, tb, 0, stream>>>(Wk, Wkb, n8w);
        cvt_kernel<<<n8w / 256, tb, 0, stream>>>(Wv, Wvb, n8w);
        cvt_kernel<<<n8w / 256, tb, 0, stream>>>(Wo, Wob, n8w);
        cvt_kernel<<<n8b / 256, tb, 0, stream>>>(Q, Xq, n8b);
        cvt_kernel<<<n8b / 256, tb, 0, stream>>>(K, Xk, n8b);
        cvt_kernel<<<n8b / 256, tb, 0, stream>>>(V, Xv, n8b);

        gemm_fused<<<dim3(64, 8, 3), tb, 0, stream>>>(
            Wqb, Xq, bq, Qh, 0,
            Wkb, Xk, bk, Kh, 0,
            Xv, Wvb, bv, Vtw, 2,
            -1);

        attn_kernel<<<dim3(8, 64), tb, 0, stream>>>(Qh, Kh, Vtw, Ctx);

        gemm_fused<<<dim3(64, 8, 1), tb, 0, stream>>>(
            Wob, Ctx, bo, d_out, 1,
            Wob, Ctx, bo, d_out, 1,
            Wob, Ctx, bo, d_out, 1,
            0);
    } else {
        unsigned short* Xb  = (unsigned short*)d_ws;
        unsigned short* Wqb = Xb + EB;
        unsigned short* Wkb = Wqb + EW;
        unsigned short* Wvb = Wkb + EW;
        unsigned short* Wob = Wvb + EW;
        unsigned short* Qh  = Wob + EW;
        unsigned short* Kh  = Qh + EB;
        unsigned short* Vtw = Kh + EB;
        unsigned short* Ctx = Xb;            // Xb dead after V GEMM

        cvt_kernel<<<n8w / 256, tb, 0, stream>>>(Wq, Wqb, n8w);
        cvt_kernel<<<n8w / 256, tb, 0, stream>>>(Wk, Wkb, n8w);
        cvt_kernel<<<n8w / 256, tb, 0, stream>>>(Wv, Wvb, n8w);
        cvt_kernel<<<n8w / 256, tb, 0, stream>>>(Wo, Wob, n8w);

        cvt_kernel<<<n8b / 256, tb, 0, stream>>>(Q, Xb, n8b);
        gemm_fused<<<dim3(64, 8, 1), tb, 0, stream>>>(
            Wqb, Xb, bq, Qh, 0,  Wqb, Xb, bq, Qh, 0,  Wqb, Xb, bq, Qh, 0, 0);

        cvt_kernel<<<n8b / 256, tb, 0, stream>>>(K, Xb, n8b);
        gemm_fused<<<dim3(64, 8, 1), tb, 0, stream>>>(
            Wkb, Xb, bk, Kh, 0,  Wkb, Xb, bk, Kh, 0,  Wkb, Xb, bk, Kh, 0, 0);

        cvt_kernel<<<n8b / 256, tb, 0, stream>>>(V, Xb, n8b);
        gemm_fused<<<dim3(64, 8, 1), tb, 0, stream>>>(
            Xb, Wvb, bv, Vtw, 2,  Xb, Wvb, bv, Vtw, 2,  Xb, Wvb, bv, Vtw, 2, 0);

        attn_kernel<<<dim3(8, 64), tb, 0, stream>>>(Qh, Kh, Vtw, Ctx);

        gemm_fused<<<dim3(64, 8, 1), tb, 0, stream>>>(
            Wob, Ctx, bo, d_out, 1,  Wob, Ctx, bo, d_out, 1,  Wob, Ctx, bo, d_out, 1, 0);
    }
}